// Round 2
// baseline (817.606 us; speedup 1.0000x reference)
//
#include <hip/hip_runtime.h>

#define GROUPS 32
#define CPG    16
#define C_DIM  512
#define HW     1024
#define B_DIM  32

typedef __attribute__((ext_vector_type(8))) short bf16x8;
typedef __attribute__((ext_vector_type(4))) float f32x4;
typedef __attribute__((ext_vector_type(8))) unsigned short u16x8;

__device__ inline unsigned short f2bf(float f) {
  unsigned u = __builtin_bit_cast(unsigned, f);
  u += 0x7fff + ((u >> 16) & 1);   // RNE
  return (unsigned short)(u >> 16);
}
__device__ inline float bf2f(unsigned short s) {
  return __builtin_bit_cast(float, ((unsigned)s) << 16);
}

__device__ inline void mfma16(f32x4& d, bf16x8 a, bf16x8 b) {
  asm("v_mfma_f32_16x16x32_bf16 %0, %1, %2, %0" : "+v"(d) : "v"(a), "v"(b));
}

// Shared 128x128 tile compute: 4 waves (2x2), each 64x64 via 4x4 16x16x32 frags.
// As/Bs layout: [row][k] with row stride 72 (144B = 9*16B: b128-aligned, ~2-way bank).
// A frag: row = lane&15, k = kk + 8*(lane>>4) + j (contiguous).  B frag symmetric.
__device__ inline void mfma_tile(const unsigned short* As, const unsigned short* Bs,
                                 f32x4 acc[4][4], int lane, int wm, int wn) {
  int ar = (wm * 64 + (lane & 15)) * 72 + ((lane >> 4) << 3);
  int br = (wn * 64 + (lane & 15)) * 72 + ((lane >> 4) << 3);
#pragma unroll
  for (int kk = 0; kk < 64; kk += 32) {
    bf16x8 a[4], b[4];
#pragma unroll
    for (int mi = 0; mi < 4; ++mi)
      a[mi] = *(const bf16x8*)&As[ar + mi * 16 * 72 + kk];
#pragma unroll
    for (int ni = 0; ni < 4; ++ni)
      b[ni] = *(const bf16x8*)&Bs[br + ni * 16 * 72 + kk];
#pragma unroll
    for (int mi = 0; mi < 4; ++mi)
#pragma unroll
      for (int ni = 0; ni < 4; ++ni)
        mfma16(acc[mi][ni], a[mi], b[ni]);
  }
}

// ---------------- kernel 1: GroupNorm stats ----------------
__global__ __launch_bounds__(256) void gn_stats_k(const float* __restrict__ x,
                                                  float* __restrict__ mean,
                                                  float* __restrict__ rstd) {
  int blk = blockIdx.x;  // b*32+g ; group slab is contiguous 16*1024 floats
  const float4* p = (const float4*)(x + (size_t)blk * (CPG * HW));
  float s = 0.f, ss = 0.f;
  for (int i = threadIdx.x; i < CPG * HW / 4; i += 256) {
    float4 v = p[i];
    s  += v.x + v.y + v.z + v.w;
    ss += v.x * v.x + v.y * v.y + v.z * v.z + v.w * v.w;
  }
#pragma unroll
  for (int off = 32; off > 0; off >>= 1) {
    s  += __shfl_xor(s, off);
    ss += __shfl_xor(ss, off);
  }
  __shared__ float sm[8];
  int wave = threadIdx.x >> 6, lane = threadIdx.x & 63;
  if (lane == 0) { sm[wave] = s; sm[wave + 4] = ss; }
  __syncthreads();
  if (threadIdx.x == 0) {
    float S  = sm[0] + sm[1] + sm[2] + sm[3];
    float SS = sm[4] + sm[5] + sm[6] + sm[7];
    float mu  = S * (1.f / (CPG * HW));
    float var = SS * (1.f / (CPG * HW)) - mu * mu;
    mean[blk] = mu;
    rstd[blk] = rsqrtf(var + 1e-5f);
  }
}

// ---------------- kernel 2: fused GN-normalize + QKV GEMM ----------------
// qkv[o][p] = sum_c qkv_w[o][c] * hnorm[c][p] + qkv_b[o]; store q*sc,k*sc,v bf16
__global__ __launch_bounds__(256) void qkv_gemm_k(
    const float* __restrict__ x, const float* __restrict__ gamma,
    const float* __restrict__ beta, const float* __restrict__ qkv_w,
    const float* __restrict__ qkv_b, const float* __restrict__ mean,
    const float* __restrict__ rstd, unsigned short* __restrict__ q,
    unsigned short* __restrict__ kx, unsigned short* __restrict__ vx) {
  __shared__ unsigned short As[128 * 72];
  __shared__ unsigned short Bs[128 * 72];
  int b = blockIdx.z;
  int o0 = blockIdx.x * 128;
  int p0 = blockIdx.y * 128;
  int tid = threadIdx.x;
  int lane = tid & 63, wave = tid >> 6, wm = wave >> 1, wn = wave & 1;
  f32x4 acc[4][4] = {};
  const float* xb = x + (size_t)b * C_DIM * HW;
  for (int kt = 0; kt < C_DIM; kt += 64) {
    __syncthreads();
    {  // stage A: qkv_w[o0..+128][kt..+64] -> bf16 As[o][c]
      int c4 = (tid & 15) * 4, orow = tid >> 4;
#pragma unroll
      for (int pass = 0; pass < 8; ++pass) {
        int o = orow + pass * 16;
        float4 w4 = *(const float4*)&qkv_w[(size_t)(o0 + o) * C_DIM + kt + c4];
        unsigned short* d = &As[o * 72 + c4];
        d[0] = f2bf(w4.x); d[1] = f2bf(w4.y); d[2] = f2bf(w4.z); d[3] = f2bf(w4.w);
      }
    }
    {  // stage B: normalize x on the fly -> Bs[p][c] (transposed)
      int p4 = (tid & 31) * 4, crow = tid >> 5;
#pragma unroll
      for (int pass = 0; pass < 8; ++pass) {
        int c = crow + pass * 8;
        int cg = kt + c;
        float rs = rstd[b * GROUPS + (cg >> 4)];
        float ga = gamma[cg] * rs;
        float be = beta[cg] - mean[b * GROUPS + (cg >> 4)] * ga;
        float4 x4 = *(const float4*)&xb[(size_t)cg * HW + p0 + p4];
        Bs[(p4 + 0) * 72 + c] = f2bf(x4.x * ga + be);
        Bs[(p4 + 1) * 72 + c] = f2bf(x4.y * ga + be);
        Bs[(p4 + 2) * 72 + c] = f2bf(x4.z * ga + be);
        Bs[(p4 + 3) * 72 + c] = f2bf(x4.w * ga + be);
      }
    }
    __syncthreads();
    mfma_tile(As, Bs, acc, lane, wm, wn);
  }
  const float SC = 0.21022410381342863f;  // 512^-0.25, folded into q and k
#pragma unroll
  for (int mi = 0; mi < 4; ++mi)
#pragma unroll
    for (int ni = 0; ni < 4; ++ni) {
      int p = p0 + wn * 64 + ni * 16 + (lane & 15);
#pragma unroll
      for (int r = 0; r < 4; ++r) {
        int oo = o0 + wm * 64 + mi * 16 + ((lane >> 4) << 2) + r;
        float val = acc[mi][ni][r] + qkv_b[oo];
        if (oo < 512)
          q[((size_t)b * C_DIM + oo) * HW + p] = f2bf(val * SC);
        else if (oo < 1024)
          kx[((size_t)b * C_DIM + (oo - 512)) * HW + p] = f2bf(val * SC);
        else
          vx[((size_t)b * C_DIM + (oo - 1024)) * HW + p] = f2bf(val);
      }
    }
}

// ---------------- kernel 3a: S = q^T k (contraction over c) ----------------
__global__ __launch_bounds__(256) void qk_gemm_k(const unsigned short* __restrict__ q,
                                                 const unsigned short* __restrict__ kx,
                                                 unsigned short* __restrict__ S) {
  __shared__ unsigned short As[128 * 72];
  __shared__ unsigned short Bs[128 * 72];
  int b = blockIdx.z;
  int i0 = blockIdx.x * 128, j0 = blockIdx.y * 128;
  int tid = threadIdx.x;
  int lane = tid & 63, wave = tid >> 6, wm = wave >> 1, wn = wave & 1;
  f32x4 acc[4][4] = {};
  const unsigned short* qb = q + (size_t)b * C_DIM * HW;
  const unsigned short* kb = kx + (size_t)b * C_DIM * HW;
  for (int kt = 0; kt < C_DIM; kt += 64) {
    __syncthreads();
    int i4 = (tid & 31) * 4, crow = tid >> 5;
#pragma unroll
    for (int pass = 0; pass < 8; ++pass) {
      int c = crow + pass * 8;
      ushort4 a4 = *(const ushort4*)&qb[(size_t)(kt + c) * HW + i0 + i4];
      As[(i4 + 0) * 72 + c] = a4.x; As[(i4 + 1) * 72 + c] = a4.y;
      As[(i4 + 2) * 72 + c] = a4.z; As[(i4 + 3) * 72 + c] = a4.w;
      ushort4 b4 = *(const ushort4*)&kb[(size_t)(kt + c) * HW + j0 + i4];
      Bs[(i4 + 0) * 72 + c] = b4.x; Bs[(i4 + 1) * 72 + c] = b4.y;
      Bs[(i4 + 2) * 72 + c] = b4.z; Bs[(i4 + 3) * 72 + c] = b4.w;
    }
    __syncthreads();
    mfma_tile(As, Bs, acc, lane, wm, wn);
  }
  unsigned short* Sb = S + (size_t)b * HW * HW;
#pragma unroll
  for (int mi = 0; mi < 4; ++mi)
#pragma unroll
    for (int ni = 0; ni < 4; ++ni) {
      int j = j0 + wn * 64 + ni * 16 + (lane & 15);
#pragma unroll
      for (int r = 0; r < 4; ++r) {
        int i = i0 + wm * 64 + mi * 16 + ((lane >> 4) << 2) + r;
        Sb[(size_t)i * HW + j] = f2bf(acc[mi][ni][r]);
      }
    }
}

// ---------------- kernel 3b: row softmax, in place, one wave per row ----------------
__global__ __launch_bounds__(256) void softmax_k(unsigned short* __restrict__ S) {
  int row = blockIdx.x * 4 + (threadIdx.x >> 6);
  int lane = threadIdx.x & 63;
  unsigned short* rp = S + (size_t)row * HW + lane * 16;
  u16x8 a = *(const u16x8*)rp;
  u16x8 c = *(const u16x8*)(rp + 8);
  float f[16];
#pragma unroll
  for (int u = 0; u < 8; ++u) { f[u] = bf2f(a[u]); f[u + 8] = bf2f(c[u]); }
  float m = f[0];
#pragma unroll
  for (int u = 1; u < 16; ++u) m = fmaxf(m, f[u]);
#pragma unroll
  for (int off = 32; off > 0; off >>= 1) m = fmaxf(m, __shfl_xor(m, off));
  float s = 0.f;
#pragma unroll
  for (int u = 0; u < 16; ++u) { f[u] = __expf(f[u] - m); s += f[u]; }
#pragma unroll
  for (int off = 32; off > 0; off >>= 1) s += __shfl_xor(s, off);
  float inv = 1.0f / s;
#pragma unroll
  for (int u = 0; u < 8; ++u) { a[u] = f2bf(f[u] * inv); c[u] = f2bf(f[u + 8] * inv); }
  *(u16x8*)rp = a;
  *(u16x8*)(rp + 8) = c;
}

// ---------------- kernel 3c: O[c][i] = sum_j v[c][j] * P[i][j] ----------------
__global__ __launch_bounds__(256) void pv_gemm_k(const unsigned short* __restrict__ vx,
                                                 const unsigned short* __restrict__ P,
                                                 unsigned short* __restrict__ ha) {
  __shared__ unsigned short As[128 * 72];
  __shared__ unsigned short Bs[128 * 72];
  int b = blockIdx.z;
  int c0 = blockIdx.x * 128, i0 = blockIdx.y * 128;
  int tid = threadIdx.x;
  int lane = tid & 63, wave = tid >> 6, wm = wave >> 1, wn = wave & 1;
  f32x4 acc[4][4] = {};
  const unsigned short* vb = vx + (size_t)b * C_DIM * HW;
  const unsigned short* Pb = P + (size_t)b * HW * HW;
  for (int kt = 0; kt < HW; kt += 64) {
    __syncthreads();
    int j4 = (tid & 15) * 4, row = tid >> 4;
#pragma unroll
    for (int pass = 0; pass < 8; ++pass) {
      int rr = row + pass * 16;
      *(ushort4*)&As[rr * 72 + j4] = *(const ushort4*)&vb[(size_t)(c0 + rr) * HW + kt + j4];
      *(ushort4*)&Bs[rr * 72 + j4] = *(const ushort4*)&Pb[(size_t)(i0 + rr) * HW + kt + j4];
    }
    __syncthreads();
    mfma_tile(As, Bs, acc, lane, wm, wn);
  }
#pragma unroll
  for (int mi = 0; mi < 4; ++mi)
#pragma unroll
    for (int ni = 0; ni < 4; ++ni) {
      int i = i0 + wn * 64 + ni * 16 + (lane & 15);
#pragma unroll
      for (int r = 0; r < 4; ++r) {
        int cc = c0 + wm * 64 + mi * 16 + ((lane >> 4) << 2) + r;
        ha[((size_t)b * C_DIM + cc) * HW + i] = f2bf(acc[mi][ni][r]);
      }
    }
}

// ---------------- kernel 4: out = x + proj_w @ O + proj_b ----------------
__global__ __launch_bounds__(256) void proj_gemm_k(const float* __restrict__ x,
                                                   const unsigned short* __restrict__ ha,
                                                   const float* __restrict__ proj_w,
                                                   const float* __restrict__ proj_b,
                                                   float* __restrict__ out) {
  __shared__ unsigned short As[128 * 72];
  __shared__ unsigned short Bs[128 * 72];
  int b = blockIdx.z;
  int o0 = blockIdx.x * 128, p0 = blockIdx.y * 128;
  int tid = threadIdx.x;
  int lane = tid & 63, wave = tid >> 6, wm = wave >> 1, wn = wave & 1;
  f32x4 acc[4][4] = {};
  const unsigned short* hb = ha + (size_t)b * C_DIM * HW;
  for (int kt = 0; kt < C_DIM; kt += 64) {
    __syncthreads();
    {
      int c4 = (tid & 15) * 4, orow = tid >> 4;
#pragma unroll
      for (int pass = 0; pass < 8; ++pass) {
        int o = orow + pass * 16;
        float4 w4 = *(const float4*)&proj_w[(size_t)(o0 + o) * C_DIM + kt + c4];
        unsigned short* d = &As[o * 72 + c4];
        d[0] = f2bf(w4.x); d[1] = f2bf(w4.y); d[2] = f2bf(w4.z); d[3] = f2bf(w4.w);
      }
    }
    {
      int p4 = (tid & 31) * 4, crow = tid >> 5;
#pragma unroll
      for (int pass = 0; pass < 8; ++pass) {
        int c = crow + pass * 8;
        ushort4 h4 = *(const ushort4*)&hb[(size_t)(kt + c) * HW + p0 + p4];
        Bs[(p4 + 0) * 72 + c] = h4.x; Bs[(p4 + 1) * 72 + c] = h4.y;
        Bs[(p4 + 2) * 72 + c] = h4.z; Bs[(p4 + 3) * 72 + c] = h4.w;
      }
    }
    __syncthreads();
    mfma_tile(As, Bs, acc, lane, wm, wn);
  }
  const float* xb = x + (size_t)b * C_DIM * HW;
  float* ob = out + (size_t)b * C_DIM * HW;
#pragma unroll
  for (int mi = 0; mi < 4; ++mi)
#pragma unroll
    for (int ni = 0; ni < 4; ++ni) {
      int p = p0 + wn * 64 + ni * 16 + (lane & 15);
#pragma unroll
      for (int r = 0; r < 4; ++r) {
        int o = o0 + wm * 64 + mi * 16 + ((lane >> 4) << 2) + r;
        size_t idx = (size_t)o * HW + p;
        ob[idx] = xb[idx] + acc[mi][ni][r] + proj_b[o];
      }
    }
}

extern "C" void kernel_launch(void* const* d_in, const int* in_sizes, int n_in,
                              void* d_out, int out_size, void* d_ws, size_t ws_size,
                              hipStream_t stream) {
  const float* x      = (const float*)d_in[0];
  const float* gamma  = (const float*)d_in[1];
  const float* beta   = (const float*)d_in[2];
  const float* qkv_w  = (const float*)d_in[3];
  const float* qkv_b  = (const float*)d_in[4];
  const float* proj_w = (const float*)d_in[5];
  const float* proj_b = (const float*)d_in[6];
  float* out = (float*)d_out;

  // workspace: mean(4K) rstd(4K) q/k/v/ha (bf16, 32MB each) S (bf16, 64MB) ~= 192MB
  char* ws = (char*)d_ws;
  float* mean = (float*)ws;
  float* rstd = (float*)(ws + 4096);
  unsigned short* q  = (unsigned short*)(ws + 8192);
  unsigned short* kx = q  + (size_t)B_DIM * C_DIM * HW;
  unsigned short* vx = kx + (size_t)B_DIM * C_DIM * HW;
  unsigned short* ha = vx + (size_t)B_DIM * C_DIM * HW;
  unsigned short* S  = ha + (size_t)B_DIM * C_DIM * HW;

  gn_stats_k<<<dim3(B_DIM * GROUPS), dim3(256), 0, stream>>>(x, mean, rstd);
  qkv_gemm_k<<<dim3(12, 8, B_DIM), dim3(256), 0, stream>>>(x, gamma, beta, qkv_w, qkv_b,
                                                           mean, rstd, q, kx, vx);
  qk_gemm_k<<<dim3(8, 8, B_DIM), dim3(256), 0, stream>>>(q, kx, S);
  softmax_k<<<dim3(B_DIM * HW / 4), dim3(256), 0, stream>>>(S);
  pv_gemm_k<<<dim3(4, 8, B_DIM), dim3(256), 0, stream>>>(vx, S, ha);
  proj_gemm_k<<<dim3(4, 8, B_DIM), dim3(256), 0, stream>>>(x, ha, proj_w, proj_b, out);
}

// Round 4
// 395.949 us; speedup vs baseline: 2.0649x; 2.0649x over previous
//
#include <hip/hip_runtime.h>

#define GROUPS 32
#define CPG    16
#define C_DIM  512
#define HW     1024
#define B_DIM  32

typedef __attribute__((ext_vector_type(8))) short bf16x8;
typedef __attribute__((ext_vector_type(4))) float f32x4;
typedef __attribute__((ext_vector_type(8))) unsigned short u16x8;

__device__ inline unsigned short f2bf(float f) {
  unsigned u = __builtin_bit_cast(unsigned, f);
  u += 0x7fff + ((u >> 16) & 1);   // RNE
  return (unsigned short)(u >> 16);
}
__device__ inline float bf2f(unsigned short s) {
  return __builtin_bit_cast(float, ((unsigned)s) << 16);
}

__device__ inline void mfma16(f32x4& d, bf16x8 a, bf16x8 b) {
  asm("v_mfma_f32_16x16x32_bf16 %0, %1, %2, %0" : "+v"(d) : "v"(a), "v"(b));
}

// async global->LDS: stages 128 rows x 64 cols (bf16) linearly. LDS dest is
// wave-uniform base + lane*16 (HW rule); global src per-lane. Row r=(lane>>3),
// 16B chunk (lane&7) -> lds offset lane*16 == (r*64 + (lane&7)*8) shorts. Linear.
__device__ inline void stage128x64(const unsigned short* g0, size_t rowStride,
                                   unsigned short* lds, int wave, int lane) {
  int r  = lane >> 3;
  int k8 = (lane & 7) * 8;
#pragma unroll
  for (int i = 0; i < 4; ++i) {
    const unsigned short* g = g0 + (size_t)(wave * 32 + i * 8 + r) * rowStride + k8;
    unsigned short* l = lds + (wave * 32 + i * 8) * 64;
    __builtin_amdgcn_global_load_lds((const __attribute__((address_space(1))) void*)g,
                                     (__attribute__((address_space(3))) void*)l, 16, 0, 0);
  }
}

// 128x128 tile: 4 waves (2x2), each 64x64 via 4x4 16x16x32 frags. LDS [row][64].
__device__ inline void mfma_tile64(const unsigned short* As, const unsigned short* Bs,
                                   f32x4 acc[4][4], int lane, int wm, int wn) {
  int ar = (wm * 64 + (lane & 15)) * 64 + ((lane >> 4) << 3);
  int br = (wn * 64 + (lane & 15)) * 64 + ((lane >> 4) << 3);
#pragma unroll
  for (int kk = 0; kk < 64; kk += 32) {
    bf16x8 a[4], b[4];
#pragma unroll
    for (int mi = 0; mi < 4; ++mi) a[mi] = *(const bf16x8*)&As[ar + mi * 16 * 64 + kk];
#pragma unroll
    for (int ni = 0; ni < 4; ++ni) b[ni] = *(const bf16x8*)&Bs[br + ni * 16 * 64 + kk];
#pragma unroll
    for (int mi = 0; mi < 4; ++mi)
#pragma unroll
      for (int ni = 0; ni < 4; ++ni) mfma16(acc[mi][ni], a[mi], b[ni]);
  }
}

// ---------------- kernel 1: GroupNorm stats ----------------
__global__ __launch_bounds__(256) void gn_stats_k(const float* __restrict__ x,
                                                  float* __restrict__ mean,
                                                  float* __restrict__ rstd) {
  int blk = blockIdx.x;  // b*32+g ; group slab is contiguous 16*1024 floats
  const float4* p = (const float4*)(x + (size_t)blk * (CPG * HW));
  float s = 0.f, ss = 0.f;
  for (int i = threadIdx.x; i < CPG * HW / 4; i += 256) {
    float4 v = p[i];
    s  += v.x + v.y + v.z + v.w;
    ss += v.x * v.x + v.y * v.y + v.z * v.z + v.w * v.w;
  }
#pragma unroll
  for (int off = 32; off > 0; off >>= 1) {
    s  += __shfl_xor(s, off);
    ss += __shfl_xor(ss, off);
  }
  __shared__ float sm[8];
  int wave = threadIdx.x >> 6, lane = threadIdx.x & 63;
  if (lane == 0) { sm[wave] = s; sm[wave + 4] = ss; }
  __syncthreads();
  if (threadIdx.x == 0) {
    float S  = sm[0] + sm[1] + sm[2] + sm[3];
    float SS = sm[4] + sm[5] + sm[6] + sm[7];
    float mu  = S * (1.f / (CPG * HW));
    float var = SS * (1.f / (CPG * HW)) - mu * mu;
    mean[blk] = mu;
    rstd[blk] = rsqrtf(var + 1e-5f);
  }
}

// ---------------- kernel 2: weights -> bf16 (attn scale folded into q,k) ----------------
__global__ __launch_bounds__(256) void prep_k(const float* __restrict__ qkv_w,
                                              const float* __restrict__ qkv_b,
                                              const float* __restrict__ proj_w,
                                              unsigned short* __restrict__ wq_bf,
                                              unsigned short* __restrict__ pw_bf,
                                              float* __restrict__ b_s) {
  const float SC = 0.21022410381342863f;  // 512^-0.25
  int t = blockIdx.x * 256 + threadIdx.x;
  for (int i = t; i < 1536 * 512 / 4; i += gridDim.x * 256) {
    float4 w = *(const float4*)&qkv_w[i * 4];
    float sc = (i * 4 < 1024 * 512) ? SC : 1.f;
    ushort4 o;
    o.x = f2bf(w.x * sc); o.y = f2bf(w.y * sc); o.z = f2bf(w.z * sc); o.w = f2bf(w.w * sc);
    *(ushort4*)&wq_bf[i * 4] = o;
  }
  for (int i = t; i < 512 * 512 / 4; i += gridDim.x * 256) {
    float4 w = *(const float4*)&proj_w[i * 4];
    ushort4 o;
    o.x = f2bf(w.x); o.y = f2bf(w.y); o.z = f2bf(w.z); o.w = f2bf(w.w);
    *(ushort4*)&pw_bf[i * 4] = o;
  }
  if (t < 1536) b_s[t] = qkv_b[t] * (t < 1024 ? SC : 1.f);
}

// ---------------- kernel 3: GN-normalize + transpose -> hn_t[b][p][c] bf16 ----------------
__global__ __launch_bounds__(256) void gn_apply_t_k(const float* __restrict__ x,
                                                    const float* __restrict__ gamma,
                                                    const float* __restrict__ beta,
                                                    const float* __restrict__ mean,
                                                    const float* __restrict__ rstd,
                                                    unsigned short* __restrict__ hn_t) {
  __shared__ unsigned short Ls[64 * 68];
  int b = blockIdx.z, p0 = blockIdx.x * 64, c0 = blockIdx.y * 64;
  int tid = threadIdx.x;
  int c_loc = tid >> 4, p4 = (tid & 15) * 4;
#pragma unroll
  for (int cc = 0; cc < 4; ++cc) {
    int c = c_loc + cc * 16;
    int cg = c0 + c;
    float rs = rstd[b * GROUPS + (cg >> 4)];
    float ga = gamma[cg] * rs;
    float be = beta[cg] - mean[b * GROUPS + (cg >> 4)] * ga;
    float4 x4 = *(const float4*)&x[((size_t)b * C_DIM + cg) * HW + p0 + p4];
    ushort4 o;
    o.x = f2bf(x4.x * ga + be); o.y = f2bf(x4.y * ga + be);
    o.z = f2bf(x4.z * ga + be); o.w = f2bf(x4.w * ga + be);
    *(ushort4*)&Ls[c * 68 + p4] = o;
  }
  __syncthreads();
#pragma unroll
  for (int pass = 0; pass < 2; ++pass) {
    int cid = tid + pass * 256;       // 512 chunks: 64 p-rows x 8 c8
    int p = cid >> 3, c8 = cid & 7;
    u16x8 o;
#pragma unroll
    for (int u = 0; u < 8; ++u) o[u] = Ls[(c8 * 8 + u) * 68 + p];
    *(u16x8*)&hn_t[((size_t)b * HW + p0 + p) * C_DIM + c0 + c8 * 8] = o;
  }
}

// ---------------- kernel 4: QKV GEMM (A=wq_bf[o][c], B=hn_t[p][c]) ----------------
// writes q_t,k_t [b][p][c] (scale+bias folded), v [b][c][p]
__global__ __launch_bounds__(256) void qkv_gemm_k(
    const unsigned short* __restrict__ wq_bf, const unsigned short* __restrict__ hn_t,
    const float* __restrict__ b_s, unsigned short* __restrict__ q_t,
    unsigned short* __restrict__ k_t, unsigned short* __restrict__ vx) {
  __shared__ __align__(16) unsigned short As[128 * 64];
  __shared__ __align__(16) unsigned short Bs[128 * 64];
  int b = blockIdx.z, o0 = blockIdx.x * 128, p0 = blockIdx.y * 128;
  int tid = threadIdx.x, lane = tid & 63, wave = tid >> 6, wm = wave >> 1, wn = wave & 1;
  f32x4 acc[4][4] = {};
  const unsigned short* hb = hn_t + (size_t)b * HW * C_DIM;
  for (int kt = 0; kt < C_DIM; kt += 64) {
    __syncthreads();
    stage128x64(wq_bf + (size_t)o0 * C_DIM + kt, C_DIM, As, wave, lane);
    stage128x64(hb + (size_t)p0 * C_DIM + kt, C_DIM, Bs, wave, lane);
    __syncthreads();
    mfma_tile64(As, Bs, acc, lane, wm, wn);
  }
  // region is block-uniform: x-blocks 0-3 -> q, 4-7 -> k, 8-11 -> v
#pragma unroll
  for (int mi = 0; mi < 4; ++mi) {
    int obase = o0 + wm * 64 + mi * 16 + ((lane >> 4) << 2);
    float4 bias = *(const float4*)&b_s[obase];
#pragma unroll
    for (int ni = 0; ni < 4; ++ni) {
      int p = p0 + wn * 64 + ni * 16 + (lane & 15);
      if (o0 < 512) {
        ushort4 o;
        o.x = f2bf(acc[mi][ni][0] + bias.x); o.y = f2bf(acc[mi][ni][1] + bias.y);
        o.z = f2bf(acc[mi][ni][2] + bias.z); o.w = f2bf(acc[mi][ni][3] + bias.w);
        *(ushort4*)&q_t[((size_t)b * HW + p) * C_DIM + obase] = o;
      } else if (o0 < 1024) {
        ushort4 o;
        o.x = f2bf(acc[mi][ni][0] + bias.x); o.y = f2bf(acc[mi][ni][1] + bias.y);
        o.z = f2bf(acc[mi][ni][2] + bias.z); o.w = f2bf(acc[mi][ni][3] + bias.w);
        *(ushort4*)&k_t[((size_t)b * HW + p) * C_DIM + obase - 512] = o;
      } else {
        float bb[4] = {bias.x, bias.y, bias.z, bias.w};
#pragma unroll
        for (int r = 0; r < 4; ++r)
          vx[((size_t)b * C_DIM + obase - 1024 + r) * HW + p] = f2bf(acc[mi][ni][r] + bb[r]);
      }
    }
  }
}

// ---------------- kernel 5: S = q k^T (A=q_t[i][c], B=k_t[j][c]) ----------------
__global__ __launch_bounds__(256) void qk_gemm_k(const unsigned short* __restrict__ q_t,
                                                 const unsigned short* __restrict__ k_t,
                                                 unsigned short* __restrict__ S) {
  __shared__ __align__(16) unsigned short As[128 * 64];
  __shared__ __align__(16) unsigned short Bs[128 * 64];
  int b = blockIdx.z, i0 = blockIdx.x * 128, j0 = blockIdx.y * 128;
  int tid = threadIdx.x, lane = tid & 63, wave = tid >> 6, wm = wave >> 1, wn = wave & 1;
  f32x4 acc[4][4] = {};
  const unsigned short* qb = q_t + (size_t)b * HW * C_DIM;
  const unsigned short* kb = k_t + (size_t)b * HW * C_DIM;
  for (int kt = 0; kt < C_DIM; kt += 64) {
    __syncthreads();
    stage128x64(qb + (size_t)i0 * C_DIM + kt, C_DIM, As, wave, lane);
    stage128x64(kb + (size_t)j0 * C_DIM + kt, C_DIM, Bs, wave, lane);
    __syncthreads();
    mfma_tile64(As, Bs, acc, lane, wm, wn);
  }
  unsigned short* Sb = S + (size_t)b * HW * HW;
#pragma unroll
  for (int mi = 0; mi < 4; ++mi)
#pragma unroll
    for (int ni = 0; ni < 4; ++ni) {
      int j = j0 + wn * 64 + ni * 16 + (lane & 15);
#pragma unroll
      for (int r = 0; r < 4; ++r) {
        int i = i0 + wm * 64 + mi * 16 + ((lane >> 4) << 2) + r;
        Sb[(size_t)i * HW + j] = f2bf(acc[mi][ni][r]);
      }
    }
}

// ---------------- kernel 6: row softmax, in place ----------------
__global__ __launch_bounds__(256) void softmax_k(unsigned short* __restrict__ S) {
  int row = blockIdx.x * 4 + (threadIdx.x >> 6);
  int lane = threadIdx.x & 63;
  unsigned short* rp = S + (size_t)row * HW + lane * 16;
  u16x8 a = *(const u16x8*)rp;
  u16x8 c = *(const u16x8*)(rp + 8);
  float f[16];
#pragma unroll
  for (int u = 0; u < 8; ++u) { f[u] = bf2f(a[u]); f[u + 8] = bf2f(c[u]); }
  float m = f[0];
#pragma unroll
  for (int u = 1; u < 16; ++u) m = fmaxf(m, f[u]);
#pragma unroll
  for (int off = 32; off > 0; off >>= 1) m = fmaxf(m, __shfl_xor(m, off));
  float s = 0.f;
#pragma unroll
  for (int u = 0; u < 16; ++u) { f[u] = __expf(f[u] - m); s += f[u]; }
#pragma unroll
  for (int off = 32; off > 0; off >>= 1) s += __shfl_xor(s, off);
  float inv = 1.0f / s;
#pragma unroll
  for (int u = 0; u < 8; ++u) { a[u] = f2bf(f[u] * inv); c[u] = f2bf(f[u + 8] * inv); }
  *(u16x8*)rp = a;
  *(u16x8*)(rp + 8) = c;
}

// ---------------- kernel 7: O^T[i][c] = sum_j P[i][j] v[c][j] ----------------
__global__ __launch_bounds__(256) void pv_gemm_k(const unsigned short* __restrict__ P,
                                                 const unsigned short* __restrict__ vx,
                                                 unsigned short* __restrict__ ha_t) {
  __shared__ __align__(16) unsigned short As[128 * 64];
  __shared__ __align__(16) unsigned short Bs[128 * 64];
  int b = blockIdx.z, i0 = blockIdx.x * 128, c0 = blockIdx.y * 128;
  int tid = threadIdx.x, lane = tid & 63, wave = tid >> 6, wm = wave >> 1, wn = wave & 1;
  f32x4 acc[4][4] = {};
  const unsigned short* Pb = P + (size_t)b * HW * HW;
  const unsigned short* vb = vx + (size_t)b * C_DIM * HW;
  for (int kt = 0; kt < HW; kt += 64) {
    __syncthreads();
    stage128x64(Pb + (size_t)i0 * HW + kt, HW, As, wave, lane);
    stage128x64(vb + (size_t)c0 * HW + kt, HW, Bs, wave, lane);
    __syncthreads();
    mfma_tile64(As, Bs, acc, lane, wm, wn);
  }
#pragma unroll
  for (int mi = 0; mi < 4; ++mi)
#pragma unroll
    for (int ni = 0; ni < 4; ++ni) {
      int c = c0 + wn * 64 + ni * 16 + (lane & 15);
#pragma unroll
      for (int r = 0; r < 4; ++r) {
        int i = i0 + wm * 64 + mi * 16 + ((lane >> 4) << 2) + r;
        ha_t[((size_t)b * HW + i) * C_DIM + c] = f2bf(acc[mi][ni][r]);
      }
    }
}

// ---------------- kernel 8: out = x + proj_w @ O + proj_b ----------------
__global__ __launch_bounds__(256) void proj_gemm_k(const float* __restrict__ x,
                                                   const unsigned short* __restrict__ ha_t,
                                                   const unsigned short* __restrict__ pw_bf,
                                                   const float* __restrict__ proj_b,
                                                   float* __restrict__ out) {
  __shared__ __align__(16) unsigned short As[128 * 64];
  __shared__ __align__(16) unsigned short Bs[128 * 64];
  int b = blockIdx.z, o0 = blockIdx.x * 128, p0 = blockIdx.y * 128;
  int tid = threadIdx.x, lane = tid & 63, wave = tid >> 6, wm = wave >> 1, wn = wave & 1;
  f32x4 acc[4][4] = {};
  const unsigned short* hb = ha_t + (size_t)b * HW * C_DIM;
  for (int kt = 0; kt < C_DIM; kt += 64) {
    __syncthreads();
    stage128x64(pw_bf + (size_t)o0 * C_DIM + kt, C_DIM, As, wave, lane);
    stage128x64(hb + (size_t)p0 * C_DIM + kt, C_DIM, Bs, wave, lane);
    __syncthreads();
    mfma_tile64(As, Bs, acc, lane, wm, wn);
  }
  const float* xb = x + (size_t)b * C_DIM * HW;
  float* ob = out + (size_t)b * C_DIM * HW;
#pragma unroll
  for (int mi = 0; mi < 4; ++mi)
#pragma unroll
    for (int ni = 0; ni < 4; ++ni) {
      int p = p0 + wn * 64 + ni * 16 + (lane & 15);
#pragma unroll
      for (int r = 0; r < 4; ++r) {
        int o = o0 + wm * 64 + mi * 16 + ((lane >> 4) << 2) + r;
        size_t idx = (size_t)o * HW + p;
        ob[idx] = xb[idx] + acc[mi][ni][r] + proj_b[o];
      }
    }
}

extern "C" void kernel_launch(void* const* d_in, const int* in_sizes, int n_in,
                              void* d_out, int out_size, void* d_ws, size_t ws_size,
                              hipStream_t stream) {
  const float* x      = (const float*)d_in[0];
  const float* gamma  = (const float*)d_in[1];
  const float* beta   = (const float*)d_in[2];
  const float* qkv_w  = (const float*)d_in[3];
  const float* qkv_b  = (const float*)d_in[4];
  const float* proj_w = (const float*)d_in[5];
  const float* proj_b = (const float*)d_in[6];
  float* out = (float*)d_out;

  // ws: header(4MB incl. weights) | v 32MB | ha_t 32MB | X: hn_t(32MB) / S(64MB aliased)
  // hn_t dead before qk_gemm writes S. q_t/k_t live in d_out (dead before proj writes).
  char* ws = (char*)d_ws;
  float* mean = (float*)ws;
  float* rstd = (float*)(ws + 4096);
  float* b_s  = (float*)(ws + 8192);
  unsigned short* pw_bf = (unsigned short*)(ws + 16384);
  unsigned short* wq_bf = (unsigned short*)(ws + 16384 + 512 * 512 * 2);
  unsigned short* vx   = (unsigned short*)(ws + ((size_t)4 << 20));
  unsigned short* ha_t = (unsigned short*)(ws + ((size_t)36 << 20));
  unsigned short* hn_t = (unsigned short*)(ws + ((size_t)68 << 20));
  unsigned short* S    = (unsigned short*)(ws + ((size_t)68 << 20));
  unsigned short* q_t  = (unsigned short*)d_out;
  unsigned short* k_t  = q_t + (size_t)B_DIM * HW * C_DIM;

  gn_stats_k<<<dim3(B_DIM * GROUPS), dim3(256), 0, stream>>>(x, mean, rstd);
  prep_k<<<dim3(512), dim3(256), 0, stream>>>(qkv_w, qkv_b, proj_w, wq_bf, pw_bf, b_s);
  gn_apply_t_k<<<dim3(16, 8, B_DIM), dim3(256), 0, stream>>>(x, gamma, beta, mean, rstd, hn_t);
  qkv_gemm_k<<<dim3(12, 8, B_DIM), dim3(256), 0, stream>>>(wq_bf, hn_t, b_s, q_t, k_t, vx);
  qk_gemm_k<<<dim3(8, 8, B_DIM), dim3(256), 0, stream>>>(q_t, k_t, S);
  softmax_k<<<dim3(B_DIM * HW / 4), dim3(256), 0, stream>>>(S);
  pv_gemm_k<<<dim3(8, 4, B_DIM), dim3(256), 0, stream>>>(S, vx, ha_t);
  proj_gemm_k<<<dim3(4, 8, B_DIM), dim3(256), 0, stream>>>(x, ha_t, pw_bf, proj_b, out);
}